// Round 2
// baseline (1465.713 us; speedup 1.0000x reference)
//
#include <hip/hip_runtime.h>

#define N_NODES 50000
#define N_EDGES 1600000
#define ND 16
#define ED 16
#define HID 64
#define M1 (2*ND+ED)   // 48
#define M2 (ND+ED)     // 32
#define RMAX 16

// ---------------- edge kernel: e_new = fR(concat(x[dst], x[src], e)); agg_r[r][dst] += e_new
__global__ __launch_bounds__(256) void edge_kernel(
    const float* __restrict__ x,      // [N, 16]
    const int*   __restrict__ ei,     // [2, E]
    const float* __restrict__ e,      // [E, 16]
    const float* __restrict__ W1,     // [48, 64]
    const float* __restrict__ b1,     // [64]
    const float* __restrict__ W2,     // [64, 16]
    const float* __restrict__ b2,     // [16]
    float* __restrict__ e_new,        // [E, 16]
    float* __restrict__ aggr,         // [R, N, 16]
    int rmask)                        // R-1
{
    int idx = blockIdx.x * blockDim.x + threadIdx.x;
    if (idx >= N_EDGES) return;
    int src = ei[idx];
    int dst = ei[N_EDGES + idx];

    float m[M1];
    {
        const float4* xd = reinterpret_cast<const float4*>(x) + dst * 4;
        const float4* xs = reinterpret_cast<const float4*>(x) + src * 4;
        const float4* ep = reinterpret_cast<const float4*>(e) + (size_t)idx * 4;
#pragma unroll
        for (int q = 0; q < 4; ++q) {
            float4 v = xd[q];
            m[4*q+0] = v.x; m[4*q+1] = v.y; m[4*q+2] = v.z; m[4*q+3] = v.w;
        }
#pragma unroll
        for (int q = 0; q < 4; ++q) {
            float4 v = xs[q];
            m[16+4*q+0] = v.x; m[16+4*q+1] = v.y; m[16+4*q+2] = v.z; m[16+4*q+3] = v.w;
        }
#pragma unroll
        for (int q = 0; q < 4; ++q) {
            float4 v = ep[q];
            m[32+4*q+0] = v.x; m[32+4*q+1] = v.y; m[32+4*q+2] = v.z; m[32+4*q+3] = v.w;
        }
    }

    // layer 1: h = relu(m @ W1 + b1)
    float h[HID];
#pragma unroll
    for (int j = 0; j < HID; ++j) h[j] = b1[j];
#pragma unroll 4
    for (int i = 0; i < M1; ++i) {
        float mi = m[i];
        const float* wr = W1 + i * HID;
#pragma unroll
        for (int j = 0; j < HID; ++j) h[j] = fmaf(mi, wr[j], h[j]);
    }

    // layer 2: o = relu(h) @ W2 + b2
    float o[ED];
#pragma unroll
    for (int k = 0; k < ED; ++k) o[k] = b2[k];
#pragma unroll 8
    for (int j = 0; j < HID; ++j) {
        float hj = fmaxf(h[j], 0.0f);
        const float* wr = W2 + j * ED;
#pragma unroll
        for (int k = 0; k < ED; ++k) o[k] = fmaf(hj, wr[k], o[k]);
    }

    float4* op = reinterpret_cast<float4*>(e_new) + (size_t)idx * 4;
    op[0] = make_float4(o[0], o[1], o[2],  o[3]);
    op[1] = make_float4(o[4], o[5], o[6],  o[7]);
    op[2] = make_float4(o[8], o[9], o[10], o[11]);
    op[3] = make_float4(o[12], o[13], o[14], o[15]);

    int r = idx & rmask;
    float* ag = aggr + ((size_t)r * N_NODES + dst) * ED;
#pragma unroll
    for (int k = 0; k < ED; ++k) atomicAdd(ag + k, o[k]);
}

// ---------------- node kernel: x_new = fO(concat(x, sum_r agg_r))
__global__ __launch_bounds__(256) void node_kernel(
    const float* __restrict__ x,      // [N, 16]
    const float* __restrict__ aggr,   // [R, N, 16]
    const float* __restrict__ W1,     // [32, 64]
    const float* __restrict__ b1,     // [64]
    const float* __restrict__ W2,     // [64, 16]
    const float* __restrict__ b2,     // [16]
    float* __restrict__ x_new,        // [N, 16]
    int R)
{
    int idx = blockIdx.x * blockDim.x + threadIdx.x;
    if (idx >= N_NODES) return;

    float m[M2];
    {
        const float4* xp = reinterpret_cast<const float4*>(x) + idx * 4;
#pragma unroll
        for (int q = 0; q < 4; ++q) {
            float4 v = xp[q];
            m[4*q+0] = v.x; m[4*q+1] = v.y; m[4*q+2] = v.z; m[4*q+3] = v.w;
        }
        float4 a[4];
#pragma unroll
        for (int q = 0; q < 4; ++q) a[q] = make_float4(0.f, 0.f, 0.f, 0.f);
        for (int r = 0; r < R; ++r) {
            const float4* ap = reinterpret_cast<const float4*>(aggr) +
                               ((size_t)r * N_NODES + idx) * 4;
#pragma unroll
            for (int q = 0; q < 4; ++q) {
                float4 v = ap[q];
                a[q].x += v.x; a[q].y += v.y; a[q].z += v.z; a[q].w += v.w;
            }
        }
#pragma unroll
        for (int q = 0; q < 4; ++q) {
            m[16+4*q+0] = a[q].x; m[16+4*q+1] = a[q].y;
            m[16+4*q+2] = a[q].z; m[16+4*q+3] = a[q].w;
        }
    }

    float h[HID];
#pragma unroll
    for (int j = 0; j < HID; ++j) h[j] = b1[j];
#pragma unroll 4
    for (int i = 0; i < M2; ++i) {
        float mi = m[i];
        const float* wr = W1 + i * HID;
#pragma unroll
        for (int j = 0; j < HID; ++j) h[j] = fmaf(mi, wr[j], h[j]);
    }

    float o[ED];
#pragma unroll
    for (int k = 0; k < ED; ++k) o[k] = b2[k];
#pragma unroll 8
    for (int j = 0; j < HID; ++j) {
        float hj = fmaxf(h[j], 0.0f);
        const float* wr = W2 + j * ED;
#pragma unroll
        for (int k = 0; k < ED; ++k) o[k] = fmaf(hj, wr[k], o[k]);
    }

    float4* op = reinterpret_cast<float4*>(x_new) + idx * 4;
    op[0] = make_float4(o[0], o[1], o[2],  o[3]);
    op[1] = make_float4(o[4], o[5], o[6],  o[7]);
    op[2] = make_float4(o[8], o[9], o[10], o[11]);
    op[3] = make_float4(o[12], o[13], o[14], o[15]);
}

extern "C" void kernel_launch(void* const* d_in, const int* in_sizes, int n_in,
                              void* d_out, int out_size, void* d_ws, size_t ws_size,
                              hipStream_t stream) {
    const float* x     = (const float*)d_in[0];
    const int*   ei    = (const int*)  d_in[1];
    const float* e     = (const float*)d_in[2];
    const float* fR_W1 = (const float*)d_in[3];
    const float* fR_b1 = (const float*)d_in[4];
    const float* fR_W2 = (const float*)d_in[5];
    const float* fR_b2 = (const float*)d_in[6];
    const float* fO_W1 = (const float*)d_in[7];
    const float* fO_b1 = (const float*)d_in[8];
    const float* fO_W2 = (const float*)d_in[9];
    const float* fO_b2 = (const float*)d_in[10];

    float* x_new = (float*)d_out;                               // [N, 16]
    float* e_new = (float*)d_out + (size_t)N_NODES * ND;        // [E, 16]
    float* aggr  = (float*)d_ws;                                // [R, N, 16]

    const size_t node_blk_bytes = (size_t)N_NODES * ED * sizeof(float); // 3.2 MB
    int R = 1;
    while (R < RMAX && (size_t)(R * 2) * node_blk_bytes <= ws_size) R *= 2;

    hipMemsetAsync(aggr, 0, (size_t)R * node_blk_bytes, stream);

    edge_kernel<<<N_EDGES / 256, 256, 0, stream>>>(
        x, ei, e, fR_W1, fR_b1, fR_W2, fR_b2, e_new, aggr, R - 1);

    node_kernel<<<(N_NODES + 255) / 256, 256, 0, stream>>>(
        x, aggr, fO_W1, fO_b1, fO_W2, fO_b2, x_new, R);
}

// Round 3
// 1357.222 us; speedup vs baseline: 1.0799x; 1.0799x over previous
//
#include <hip/hip_runtime.h>

#define N_NODES 50000
#define N_EDGES 1600000
#define ND 16
#define ED 16
#define HID 64
#define M1 (2*ND+ED)   // 48
#define M2 (ND+ED)     // 32
#define RMAX 8

// ---------------- edge kernel: e_new = fR(concat(x[dst], x[src], e));
// transposed scatter: aggr[(k*R + r)*N + dst] += o[k]
__global__ __launch_bounds__(256) void edge_kernel(
    const float* __restrict__ x,      // [N, 16]
    const int*   __restrict__ ei,     // [2, E]
    const float* __restrict__ e,      // [E, 16]
    const float* __restrict__ W1,     // [48, 64]
    const float* __restrict__ b1,     // [64]
    const float* __restrict__ W2,     // [64, 16]
    const float* __restrict__ b2,     // [16]
    float* __restrict__ e_new,        // [E, 16]
    float* __restrict__ aggr,         // [16, R, N] column-major over nodes
    int R, int rmask)
{
    int idx = blockIdx.x * blockDim.x + threadIdx.x;
    if (idx >= N_EDGES) return;
    int src = ei[idx];
    int dst = ei[N_EDGES + idx];

    float m[M1];
    {
        const float4* xd = reinterpret_cast<const float4*>(x) + dst * 4;
        const float4* xs = reinterpret_cast<const float4*>(x) + src * 4;
        const float4* ep = reinterpret_cast<const float4*>(e) + (size_t)idx * 4;
#pragma unroll
        for (int q = 0; q < 4; ++q) {
            float4 v = xd[q];
            m[4*q+0] = v.x; m[4*q+1] = v.y; m[4*q+2] = v.z; m[4*q+3] = v.w;
        }
#pragma unroll
        for (int q = 0; q < 4; ++q) {
            float4 v = xs[q];
            m[16+4*q+0] = v.x; m[16+4*q+1] = v.y; m[16+4*q+2] = v.z; m[16+4*q+3] = v.w;
        }
#pragma unroll
        for (int q = 0; q < 4; ++q) {
            float4 v = ep[q];
            m[32+4*q+0] = v.x; m[32+4*q+1] = v.y; m[32+4*q+2] = v.z; m[32+4*q+3] = v.w;
        }
    }

    // layer 1: h = relu(m @ W1 + b1)
    float h[HID];
#pragma unroll
    for (int j = 0; j < HID; ++j) h[j] = b1[j];
#pragma unroll 4
    for (int i = 0; i < M1; ++i) {
        float mi = m[i];
        const float* wr = W1 + i * HID;
#pragma unroll
        for (int j = 0; j < HID; ++j) h[j] = fmaf(mi, wr[j], h[j]);
    }

    // layer 2: o = relu(h) @ W2 + b2
    float o[ED];
#pragma unroll
    for (int k = 0; k < ED; ++k) o[k] = b2[k];
#pragma unroll 8
    for (int j = 0; j < HID; ++j) {
        float hj = fmaxf(h[j], 0.0f);
        const float* wr = W2 + j * ED;
#pragma unroll
        for (int k = 0; k < ED; ++k) o[k] = fmaf(hj, wr[k], o[k]);
    }

    float4* op = reinterpret_cast<float4*>(e_new) + (size_t)idx * 4;
    op[0] = make_float4(o[0], o[1], o[2],  o[3]);
    op[1] = make_float4(o[4], o[5], o[6],  o[7]);
    op[2] = make_float4(o[8], o[9], o[10], o[11]);
    op[3] = make_float4(o[12], o[13], o[14], o[15]);

    // transposed scatter: 16 atomics to 16 DIFFERENT cachelines (parallel L2 channels)
    int r = idx & rmask;
    float* ag = aggr + (size_t)r * N_NODES + dst;
#pragma unroll
    for (int k = 0; k < ED; ++k)
        atomicAdd(ag + (size_t)k * R * N_NODES, o[k]);
}

// ---------------- node kernel: x_new = fO(concat(x, sum_r aggr[:, r, idx]))
__global__ __launch_bounds__(256) void node_kernel(
    const float* __restrict__ x,      // [N, 16]
    const float* __restrict__ aggr,   // [16, R, N]
    const float* __restrict__ W1,     // [32, 64]
    const float* __restrict__ b1,     // [64]
    const float* __restrict__ W2,     // [64, 16]
    const float* __restrict__ b2,     // [16]
    float* __restrict__ x_new,        // [N, 16]
    int R)
{
    int idx = blockIdx.x * blockDim.x + threadIdx.x;
    if (idx >= N_NODES) return;

    float m[M2];
    {
        const float4* xp = reinterpret_cast<const float4*>(x) + idx * 4;
#pragma unroll
        for (int q = 0; q < 4; ++q) {
            float4 v = xp[q];
            m[4*q+0] = v.x; m[4*q+1] = v.y; m[4*q+2] = v.z; m[4*q+3] = v.w;
        }
        // coalesced column reads: for each k, consecutive threads read consecutive nodes
#pragma unroll
        for (int k = 0; k < ED; ++k) {
            float s = 0.f;
            const float* col = aggr + (size_t)k * R * N_NODES + idx;
            for (int r = 0; r < R; ++r) s += col[(size_t)r * N_NODES];
            m[16 + k] = s;
        }
    }

    float h[HID];
#pragma unroll
    for (int j = 0; j < HID; ++j) h[j] = b1[j];
#pragma unroll 4
    for (int i = 0; i < M2; ++i) {
        float mi = m[i];
        const float* wr = W1 + i * HID;
#pragma unroll
        for (int j = 0; j < HID; ++j) h[j] = fmaf(mi, wr[j], h[j]);
    }

    float o[ED];
#pragma unroll
    for (int k = 0; k < ED; ++k) o[k] = b2[k];
#pragma unroll 8
    for (int j = 0; j < HID; ++j) {
        float hj = fmaxf(h[j], 0.0f);
        const float* wr = W2 + j * ED;
#pragma unroll
        for (int k = 0; k < ED; ++k) o[k] = fmaf(hj, wr[k], o[k]);
    }

    float4* op = reinterpret_cast<float4*>(x_new) + idx * 4;
    op[0] = make_float4(o[0], o[1], o[2],  o[3]);
    op[1] = make_float4(o[4], o[5], o[6],  o[7]);
    op[2] = make_float4(o[8], o[9], o[10], o[11]);
    op[3] = make_float4(o[12], o[13], o[14], o[15]);
}

extern "C" void kernel_launch(void* const* d_in, const int* in_sizes, int n_in,
                              void* d_out, int out_size, void* d_ws, size_t ws_size,
                              hipStream_t stream) {
    const float* x     = (const float*)d_in[0];
    const int*   ei    = (const int*)  d_in[1];
    const float* e     = (const float*)d_in[2];
    const float* fR_W1 = (const float*)d_in[3];
    const float* fR_b1 = (const float*)d_in[4];
    const float* fR_W2 = (const float*)d_in[5];
    const float* fR_b2 = (const float*)d_in[6];
    const float* fO_W1 = (const float*)d_in[7];
    const float* fO_b1 = (const float*)d_in[8];
    const float* fO_W2 = (const float*)d_in[9];
    const float* fO_b2 = (const float*)d_in[10];

    float* x_new = (float*)d_out;                               // [N, 16]
    float* e_new = (float*)d_out + (size_t)N_NODES * ND;        // [E, 16]
    float* aggr  = (float*)d_ws;                                // [16, R, N]

    const size_t col_bytes = (size_t)N_NODES * sizeof(float);   // 200 KB per (k,r) column
    int R = 1;
    while (R < RMAX && (size_t)ED * (size_t)(R * 2) * col_bytes <= ws_size) R *= 2;

    hipMemsetAsync(aggr, 0, (size_t)ED * R * col_bytes, stream);

    edge_kernel<<<N_EDGES / 256, 256, 0, stream>>>(
        x, ei, e, fR_W1, fR_b1, fR_W2, fR_b2, e_new, aggr, R, R - 1);

    node_kernel<<<(N_NODES + 255) / 256, 256, 0, stream>>>(
        x, aggr, fO_W1, fO_b1, fO_W2, fO_b2, x_new, R);
}

// Round 4
// 592.811 us; speedup vs baseline: 2.4725x; 2.2895x over previous
//
#include <hip/hip_runtime.h>

#define N_NODES 50000
#define N_EDGES 1600000
#define ND 16
#define ED 16
#define HID 64
#define M1 (2*ND+ED)   // 48
#define M2 (ND+ED)     // 32

// ---------------- edge kernel: e_new = fR(concat(x[dst], x[src], e));
// + CSR slot assignment: slot[idx] = count[dst]++ (single returning int atomic)
__global__ __launch_bounds__(256) void edge_kernel(
    const float* __restrict__ x,      // [N, 16]
    const int*   __restrict__ ei,     // [2, E]
    const float* __restrict__ e,      // [E, 16]
    const float* __restrict__ W1,     // [48, 64]
    const float* __restrict__ b1,     // [64]
    const float* __restrict__ W2,     // [64, 16]
    const float* __restrict__ b2,     // [16]
    float* __restrict__ e_new,        // [E, 16]
    unsigned* __restrict__ count,     // [N] degree counters (zeroed)
    unsigned short* __restrict__ slot)// [E]
{
    int idx = blockIdx.x * blockDim.x + threadIdx.x;
    if (idx >= N_EDGES) return;
    int src = ei[idx];
    int dst = ei[N_EDGES + idx];

    // issue the returning atomic EARLY; its latency hides under the MLP
    unsigned pos = atomicAdd(count + dst, 1u);

    float m[M1];
    {
        const float4* xd = reinterpret_cast<const float4*>(x) + dst * 4;
        const float4* xs = reinterpret_cast<const float4*>(x) + src * 4;
        const float4* ep = reinterpret_cast<const float4*>(e) + (size_t)idx * 4;
#pragma unroll
        for (int q = 0; q < 4; ++q) {
            float4 v = xd[q];
            m[4*q+0] = v.x; m[4*q+1] = v.y; m[4*q+2] = v.z; m[4*q+3] = v.w;
        }
#pragma unroll
        for (int q = 0; q < 4; ++q) {
            float4 v = xs[q];
            m[16+4*q+0] = v.x; m[16+4*q+1] = v.y; m[16+4*q+2] = v.z; m[16+4*q+3] = v.w;
        }
#pragma unroll
        for (int q = 0; q < 4; ++q) {
            float4 v = ep[q];
            m[32+4*q+0] = v.x; m[32+4*q+1] = v.y; m[32+4*q+2] = v.z; m[32+4*q+3] = v.w;
        }
    }

    float h[HID];
#pragma unroll
    for (int j = 0; j < HID; ++j) h[j] = b1[j];
#pragma unroll 4
    for (int i = 0; i < M1; ++i) {
        float mi = m[i];
        const float* wr = W1 + i * HID;
#pragma unroll
        for (int j = 0; j < HID; ++j) h[j] = fmaf(mi, wr[j], h[j]);
    }

    float o[ED];
#pragma unroll
    for (int k = 0; k < ED; ++k) o[k] = b2[k];
#pragma unroll 8
    for (int j = 0; j < HID; ++j) {
        float hj = fmaxf(h[j], 0.0f);
        const float* wr = W2 + j * ED;
#pragma unroll
        for (int k = 0; k < ED; ++k) o[k] = fmaf(hj, wr[k], o[k]);
    }

    float4* op = reinterpret_cast<float4*>(e_new) + (size_t)idx * 4;
    op[0] = make_float4(o[0], o[1], o[2],  o[3]);
    op[1] = make_float4(o[4], o[5], o[6],  o[7]);
    op[2] = make_float4(o[8], o[9], o[10], o[11]);
    op[3] = make_float4(o[12], o[13], o[14], o[15]);

    slot[idx] = (unsigned short)pos;
}

// ---------------- single-block exclusive scan over count[N] -> offs[N+1]
__global__ __launch_bounds__(1024) void scan_kernel(
    const unsigned* __restrict__ count, unsigned* __restrict__ offs)
{
    __shared__ unsigned sums[1024];
    const int t = threadIdx.x;
    const int C = (N_NODES + 1023) / 1024;  // 49
    int lo = t * C;
    int hi = lo + C; if (hi > N_NODES) hi = N_NODES;
    unsigned s = 0;
    for (int i = lo; i < hi && i >= 0; ++i) s += count[i];
    sums[t] = s;
    __syncthreads();
    // Hillis-Steele inclusive scan in LDS
    for (int d = 1; d < 1024; d <<= 1) {
        unsigned v = (t >= d) ? sums[t - d] : 0u;
        __syncthreads();
        sums[t] += v;
        __syncthreads();
    }
    unsigned run = (t == 0) ? 0u : sums[t - 1];  // exclusive prefix of this chunk
    for (int i = lo; i < hi && i >= 0; ++i) { offs[i] = run; run += count[i]; }
    if (t == 1023) offs[N_NODES] = run;
}

// ---------------- fill: elist[offs[dst] + slot[idx]] = idx (no atomics)
__global__ __launch_bounds__(256) void fill_kernel(
    const int* __restrict__ ei,
    const unsigned* __restrict__ offs,
    const unsigned short* __restrict__ slot,
    unsigned* __restrict__ elist)
{
    int idx = blockIdx.x * blockDim.x + threadIdx.x;
    if (idx >= N_EDGES) return;
    int dst = ei[N_EDGES + idx];
    elist[offs[dst] + (unsigned)slot[idx]] = (unsigned)idx;
}

// ---------------- agg: 4 threads per node, gather e_new rows and sum
__global__ __launch_bounds__(256) void agg_kernel(
    const float* __restrict__ e_new,   // [E,16]
    const unsigned* __restrict__ offs, // [N+1]
    const unsigned* __restrict__ count,// [N] (final degrees)
    const unsigned* __restrict__ elist,// [E]
    float* __restrict__ agg)           // [N,16]
{
    int tid = blockIdx.x * blockDim.x + threadIdx.x;
    if (tid >= N_NODES * 4) return;
    int n = tid >> 2;
    int q = tid & 3;
    unsigned base = offs[n];
    unsigned deg  = count[n];
    const float4* ep = reinterpret_cast<const float4*>(e_new);
    float4 s = make_float4(0.f, 0.f, 0.f, 0.f);
    for (unsigned j = 0; j < deg; ++j) {
        unsigned eid = elist[base + j];
        float4 v = ep[(size_t)eid * 4 + q];
        s.x += v.x; s.y += v.y; s.z += v.z; s.w += v.w;
    }
    reinterpret_cast<float4*>(agg)[(size_t)n * 4 + q] = s;
}

// ---------------- node kernel: x_new = fO(concat(x, agg))
__global__ __launch_bounds__(256) void node_kernel(
    const float* __restrict__ x,      // [N, 16]
    const float* __restrict__ agg,    // [N, 16]
    const float* __restrict__ W1,     // [32, 64]
    const float* __restrict__ b1,     // [64]
    const float* __restrict__ W2,     // [64, 16]
    const float* __restrict__ b2,     // [16]
    float* __restrict__ x_new)        // [N, 16]
{
    int idx = blockIdx.x * blockDim.x + threadIdx.x;
    if (idx >= N_NODES) return;

    float m[M2];
    {
        const float4* xp = reinterpret_cast<const float4*>(x) + idx * 4;
        const float4* ap = reinterpret_cast<const float4*>(agg) + idx * 4;
#pragma unroll
        for (int q = 0; q < 4; ++q) {
            float4 v = xp[q];
            m[4*q+0] = v.x; m[4*q+1] = v.y; m[4*q+2] = v.z; m[4*q+3] = v.w;
        }
#pragma unroll
        for (int q = 0; q < 4; ++q) {
            float4 v = ap[q];
            m[16+4*q+0] = v.x; m[16+4*q+1] = v.y; m[16+4*q+2] = v.z; m[16+4*q+3] = v.w;
        }
    }

    float h[HID];
#pragma unroll
    for (int j = 0; j < HID; ++j) h[j] = b1[j];
#pragma unroll 4
    for (int i = 0; i < M2; ++i) {
        float mi = m[i];
        const float* wr = W1 + i * HID;
#pragma unroll
        for (int j = 0; j < HID; ++j) h[j] = fmaf(mi, wr[j], h[j]);
    }

    float o[ED];
#pragma unroll
    for (int k = 0; k < ED; ++k) o[k] = b2[k];
#pragma unroll 8
    for (int j = 0; j < HID; ++j) {
        float hj = fmaxf(h[j], 0.0f);
        const float* wr = W2 + j * ED;
#pragma unroll
        for (int k = 0; k < ED; ++k) o[k] = fmaf(hj, wr[k], o[k]);
    }

    float4* op = reinterpret_cast<float4*>(x_new) + idx * 4;
    op[0] = make_float4(o[0], o[1], o[2],  o[3]);
    op[1] = make_float4(o[4], o[5], o[6],  o[7]);
    op[2] = make_float4(o[8], o[9], o[10], o[11]);
    op[3] = make_float4(o[12], o[13], o[14], o[15]);
}

// ---------------- legacy fallback (if ws too small): direct fp32 atomics
__global__ __launch_bounds__(256) void edge_kernel_atomic(
    const float* __restrict__ x, const int* __restrict__ ei,
    const float* __restrict__ e,
    const float* __restrict__ W1, const float* __restrict__ b1,
    const float* __restrict__ W2, const float* __restrict__ b2,
    float* __restrict__ e_new, float* __restrict__ agg)
{
    int idx = blockIdx.x * blockDim.x + threadIdx.x;
    if (idx >= N_EDGES) return;
    int src = ei[idx];
    int dst = ei[N_EDGES + idx];
    float m[M1];
    const float4* xd = reinterpret_cast<const float4*>(x) + dst * 4;
    const float4* xs = reinterpret_cast<const float4*>(x) + src * 4;
    const float4* ep = reinterpret_cast<const float4*>(e) + (size_t)idx * 4;
#pragma unroll
    for (int q = 0; q < 4; ++q) { float4 v = xd[q]; m[4*q]=v.x; m[4*q+1]=v.y; m[4*q+2]=v.z; m[4*q+3]=v.w; }
#pragma unroll
    for (int q = 0; q < 4; ++q) { float4 v = xs[q]; m[16+4*q]=v.x; m[16+4*q+1]=v.y; m[16+4*q+2]=v.z; m[16+4*q+3]=v.w; }
#pragma unroll
    for (int q = 0; q < 4; ++q) { float4 v = ep[q]; m[32+4*q]=v.x; m[32+4*q+1]=v.y; m[32+4*q+2]=v.z; m[32+4*q+3]=v.w; }
    float h[HID];
#pragma unroll
    for (int j = 0; j < HID; ++j) h[j] = b1[j];
#pragma unroll 4
    for (int i = 0; i < M1; ++i) {
        float mi = m[i]; const float* wr = W1 + i * HID;
#pragma unroll
        for (int j = 0; j < HID; ++j) h[j] = fmaf(mi, wr[j], h[j]);
    }
    float o[ED];
#pragma unroll
    for (int k = 0; k < ED; ++k) o[k] = b2[k];
#pragma unroll 8
    for (int j = 0; j < HID; ++j) {
        float hj = fmaxf(h[j], 0.0f); const float* wr = W2 + j * ED;
#pragma unroll
        for (int k = 0; k < ED; ++k) o[k] = fmaf(hj, wr[k], o[k]);
    }
    float4* op = reinterpret_cast<float4*>(e_new) + (size_t)idx * 4;
    op[0] = make_float4(o[0],o[1],o[2],o[3]);
    op[1] = make_float4(o[4],o[5],o[6],o[7]);
    op[2] = make_float4(o[8],o[9],o[10],o[11]);
    op[3] = make_float4(o[12],o[13],o[14],o[15]);
    float* ag = agg + (size_t)dst * ED;
#pragma unroll
    for (int k = 0; k < ED; ++k) atomicAdd(ag + k, o[k]);
}

static inline size_t align_up(size_t v, size_t a) { return (v + a - 1) / a * a; }

extern "C" void kernel_launch(void* const* d_in, const int* in_sizes, int n_in,
                              void* d_out, int out_size, void* d_ws, size_t ws_size,
                              hipStream_t stream) {
    const float* x     = (const float*)d_in[0];
    const int*   ei    = (const int*)  d_in[1];
    const float* e     = (const float*)d_in[2];
    const float* fR_W1 = (const float*)d_in[3];
    const float* fR_b1 = (const float*)d_in[4];
    const float* fR_W2 = (const float*)d_in[5];
    const float* fR_b2 = (const float*)d_in[6];
    const float* fO_W1 = (const float*)d_in[7];
    const float* fO_b1 = (const float*)d_in[8];
    const float* fO_W2 = (const float*)d_in[9];
    const float* fO_b2 = (const float*)d_in[10];

    float* x_new = (float*)d_out;                        // [N, 16]
    float* e_new = (float*)d_out + (size_t)N_NODES * ND; // [E, 16]

    char* ws = (char*)d_ws;
    size_t o = 0;
    unsigned*       count = (unsigned*)(ws + o);       o += align_up((size_t)N_NODES * 4, 256);
    unsigned*       offs  = (unsigned*)(ws + o);       o += align_up((size_t)(N_NODES + 1) * 4, 256);
    unsigned short* slot  = (unsigned short*)(ws + o); o += align_up((size_t)N_EDGES * 2, 256);
    unsigned*       elist = (unsigned*)(ws + o);       o += align_up((size_t)N_EDGES * 4, 256);
    float*          agg   = (float*)(ws + o);          o += align_up((size_t)N_NODES * ED * 4, 256);
    const size_t need = o;

    if (ws_size >= need) {
        hipMemsetAsync(count, 0, (size_t)N_NODES * 4, stream);
        edge_kernel<<<N_EDGES / 256, 256, 0, stream>>>(
            x, ei, e, fR_W1, fR_b1, fR_W2, fR_b2, e_new, count, slot);
        scan_kernel<<<1, 1024, 0, stream>>>(count, offs);
        fill_kernel<<<N_EDGES / 256, 256, 0, stream>>>(ei, offs, slot, elist);
        agg_kernel<<<(N_NODES * 4 + 255) / 256, 256, 0, stream>>>(
            e_new, offs, count, elist, agg);
        node_kernel<<<(N_NODES + 255) / 256, 256, 0, stream>>>(
            x, agg, fO_W1, fO_b1, fO_W2, fO_b2, x_new);
    } else {
        float* agg0 = (float*)d_ws;  // [N,16]
        hipMemsetAsync(agg0, 0, (size_t)N_NODES * ED * 4, stream);
        edge_kernel_atomic<<<N_EDGES / 256, 256, 0, stream>>>(
            x, ei, e, fR_W1, fR_b1, fR_W2, fR_b2, e_new, agg0);
        node_kernel<<<(N_NODES + 255) / 256, 256, 0, stream>>>(
            x, agg0, fO_W1, fO_b1, fO_W2, fO_b2, x_new);
    }
}